// Round 1
// baseline (4722.118 us; speedup 1.0000x reference)
//
#include <hip/hip_runtime.h>

#define T_TOK 1024
#define HID 1024
#define NH 16
#define NKV 4
#define HDIM 64
#define NE 64
#define INTER 512
#define QKV_N 1536

// ---------------- RMSNorm (f32 input) ----------------
__global__ void rms_kernel(const float* __restrict__ x, const float* __restrict__ w,
                           float* __restrict__ out) {
    int t = blockIdx.x, tid = threadIdx.x;
    __shared__ float red[256];
    const float* xp = x + (size_t)t * HID;
    float v[4]; float ss = 0.f;
    for (int j = 0; j < 4; ++j) { v[j] = xp[tid * 4 + j]; ss += v[j] * v[j]; }
    red[tid] = ss; __syncthreads();
    for (int s = 128; s > 0; s >>= 1) { if (tid < s) red[tid] += red[tid + s]; __syncthreads(); }
    float r = rsqrtf(red[0] / (float)HID + 1e-6f);
    for (int j = 0; j < 4; ++j)
        out[(size_t)t * HID + tid * 4 + j] = v[j] * r * w[tid * 4 + j];
}

// ---------------- Dense GEMM: C(MxN) = A(MxK) @ B(KxN) [+ addend] ----------------
// 64(M) x 128(N) tile, 256 threads, 4x8 acc/thread, double-buffered LDS,
// register-prefetch of next K-slab overlaps compute.
__global__ __launch_bounds__(256, 2) void gemm_f32(
    const float* __restrict__ A, const float* __restrict__ B,
    float* __restrict__ C, const float* __restrict__ addend,
    int M, int N, int K) {
    int row0 = blockIdx.y * 64, col0 = blockIdx.x * 128;
    int tid = threadIdx.x;
    int tx = tid & 15, ty = tid >> 4;
    __shared__ __align__(16) float As[2][16][68];    // [k][m], pad->2-way writes (free)
    __shared__ __align__(16) float Bs[2][16][132];   // [k][n]

    // staging coords
    int rA = tid >> 2, kA = (tid & 3) * 4;           // A: row rA, k-offsets kA..kA+3
    int kB = tid >> 5, cB = (tid & 31) * 4;          // B: rows kB & kB+8, cols cB..cB+3
    const float* pa = A + (size_t)(row0 + rA) * K + kA;
    const float* pb = B + (size_t)kB * N + col0 + cB;

    float4 ra, rb0, rb1;
    ra  = *(const float4*)(pa);
    rb0 = *(const float4*)(pb);
    rb1 = *(const float4*)(pb + (size_t)8 * N);
    As[0][kA + 0][rA] = ra.x; As[0][kA + 1][rA] = ra.y;
    As[0][kA + 2][rA] = ra.z; As[0][kA + 3][rA] = ra.w;
    *(float4*)&Bs[0][kB][cB] = rb0;
    *(float4*)&Bs[0][kB + 8][cB] = rb1;
    __syncthreads();

    float acc[4][8] = {};
    int NKt = K / 16;
    for (int kt = 0; kt < NKt; ++kt) {
        int cur = kt & 1;
        bool more = (kt + 1 < NKt);
        if (more) {
            int k0 = (kt + 1) * 16;
            ra  = *(const float4*)(pa + k0);
            rb0 = *(const float4*)(pb + (size_t)k0 * N);
            rb1 = *(const float4*)(pb + (size_t)(k0 + 8) * N);
        }
#pragma unroll
        for (int kk = 0; kk < 16; ++kk) {
            float4 av = *(const float4*)&As[cur][kk][ty * 4];
            float4 b0 = *(const float4*)&Bs[cur][kk][tx * 4];
            float4 b1 = *(const float4*)&Bs[cur][kk][64 + tx * 4];
            float a[4] = {av.x, av.y, av.z, av.w};
            float b[8] = {b0.x, b0.y, b0.z, b0.w, b1.x, b1.y, b1.z, b1.w};
#pragma unroll
            for (int i = 0; i < 4; ++i)
#pragma unroll
                for (int j = 0; j < 8; ++j) acc[i][j] += a[i] * b[j];
        }
        __syncthreads();
        if (more) {
            int nb = cur ^ 1;
            As[nb][kA + 0][rA] = ra.x; As[nb][kA + 1][rA] = ra.y;
            As[nb][kA + 2][rA] = ra.z; As[nb][kA + 3][rA] = ra.w;
            *(float4*)&Bs[nb][kB][cB] = rb0;
            *(float4*)&Bs[nb][kB + 8][cB] = rb1;
        }
        __syncthreads();
    }
#pragma unroll
    for (int i = 0; i < 4; ++i) {
        size_t r = row0 + ty * 4 + i;
#pragma unroll
        for (int h = 0; h < 2; ++h) {
            size_t c = col0 + h * 64 + tx * 4;
            float4 v = make_float4(acc[i][h * 4 + 0], acc[i][h * 4 + 1],
                                   acc[i][h * 4 + 2], acc[i][h * 4 + 3]);
            if (addend) {
                const float4 ad = *(const float4*)&addend[r * N + c];
                v.x += ad.x; v.y += ad.y; v.z += ad.z; v.w += ad.w;
            }
            *(float4*)&C[r * N + c] = v;
        }
    }
}

// ---------------- per-head RMSNorm + RoPE on q,k (in-place in qkv f32) ----------------
__global__ void qk_rope_kernel(float* __restrict__ qkv, const int* __restrict__ pos,
                               const float* __restrict__ qw, const float* __restrict__ kw) {
    int b = blockIdx.x;
    int t = b / (NH + NKV), hh = b % (NH + NKV);
    int lane = threadIdx.x;
    bool isq = hh < NH;
    int off = isq ? hh * HDIM : NH * HDIM + (hh - NH) * HDIM;
    const float* w = isq ? qw : kw;
    float* p = qkv + (size_t)t * QKV_N + off;
    float x = p[lane];
    float ss = x * x;
    for (int m = 1; m < 64; m <<= 1) ss += __shfl_xor(ss, m, 64);
    float r = rsqrtf(ss / (float)HDIM + 1e-6f);
    x = x * r * w[lane];
    float partner = __shfl_xor(x, 32, 64);
    int i = lane & 31;
    float freq = expf(-(float)i * (9.21034037198f / 32.f));  // 10000^(-i/32)
    float f = (float)pos[t] * freq;
    float c = cosf(f), s = sinf(f);
    float outv = (lane < 32) ? (x * c - partner * s) : (x * c + partner * s);
    p[lane] = outv;
}

// ---------------- attention: one block per (t, head) ----------------
__global__ void attn_kernel(const float* __restrict__ qkv, float* __restrict__ attn_out) {
    int t = blockIdx.x, hh = blockIdx.y;
    int kh = hh >> 2;
    __shared__ float sq[64];
    __shared__ float sc[T_TOK];
    __shared__ float red[256];
    __shared__ float po[4][64];
    int tid = threadIdx.x;
    const float* qp = qkv + (size_t)t * QKV_N + hh * HDIM;
    if (tid < 64) sq[tid] = qp[tid];
    __syncthreads();
    int L = t + 1;
    float lmax = -1e30f;
    for (int s = tid; s < L; s += 256) {
        const float* kp = qkv + (size_t)s * QKV_N + NH * HDIM + kh * HDIM;
        float dot = 0.f;
        for (int d = 0; d < 64; ++d) dot += sq[d] * kp[d];
        dot *= 0.125f;  // 1/sqrt(64)
        sc[s] = dot;
        lmax = fmaxf(lmax, dot);
    }
    red[tid] = lmax; __syncthreads();
    for (int s = 128; s > 0; s >>= 1) { if (tid < s) red[tid] = fmaxf(red[tid], red[tid + s]); __syncthreads(); }
    float mx = red[0]; __syncthreads();
    float lsum = 0.f;
    for (int s = tid; s < L; s += 256) { float e = expf(sc[s] - mx); sc[s] = e; lsum += e; }
    red[tid] = lsum; __syncthreads();
    for (int s = 128; s > 0; s >>= 1) { if (tid < s) red[tid] += red[tid + s]; __syncthreads(); }
    float inv = 1.f / red[0];
    int grp = tid >> 6, lane = tid & 63;
    float acc = 0.f;
    for (int s = grp; s < L; s += 4)
        acc += sc[s] * qkv[(size_t)s * QKV_N + (NH + NKV) * HDIM + kh * HDIM + lane];
    po[grp][lane] = acc;
    __syncthreads();
    if (tid < 64) {
        float o = (po[0][tid] + po[1][tid] + po[2][tid] + po[3][tid]) * inv;
        attn_out[(size_t)t * HID + hh * HDIM + tid] = o;
    }
}

// ---------------- router: logits, softmax, group top-1, scatter ----------------
__global__ void route_kernel(const float* __restrict__ h2, const float* __restrict__ Wg,
                             int* __restrict__ cnt, int* __restrict__ lst_tok,
                             int* __restrict__ lst_pair, float* __restrict__ pair_w) {
    int t = blockIdx.x, j = threadIdx.x;  // 64 threads
    const float* hp = h2 + (size_t)t * HID;
    float acc = 0.f;
    for (int k = 0; k < HID; ++k) acc += hp[k] * Wg[(size_t)k * NE + j];
    float mx = acc;
    for (int m = 1; m < 64; m <<= 1) mx = fmaxf(mx, __shfl_xor(mx, m, 64));
    float e = expf(acc - mx);
    float sm = e;
    for (int m = 1; m < 64; m <<= 1) sm += __shfl_xor(sm, m, 64);
    float p = e / sm;
    float bp = p; int bi = j;
    for (int m = 1; m < 8; m <<= 1) {
        float op = __shfl_xor(bp, m, 64);
        int oi = __shfl_xor(bi, m, 64);
        if (op > bp || (op == bp && oi < bi)) { bp = op; bi = oi; }
    }
    __shared__ float gw[8]; __shared__ int gi[8];
    if ((j & 7) == 0) { gw[j >> 3] = bp; gi[j >> 3] = bi; }
    __syncthreads();
    if (j < 8) {
        float tw = gw[j];
        float wsum = tw;
        for (int m = 1; m < 8; m <<= 1) wsum += __shfl_xor(wsum, m, 64);
        float w = tw / wsum;
        int ei = gi[j];
        int pos = atomicAdd(&cnt[ei], 1);
        lst_tok[ei * T_TOK + pos] = t;
        lst_pair[ei * T_TOK + pos] = t * 8 + j;
        pair_w[t * 8 + j] = w;
    }
}

// ---------------- MoE gate_up + SiLU*up*w ----------------
// 128-token x 64-inter tile (g and u fused), z-split over token tiles,
// double-buffered LDS, 8x4(+8x4) acc per thread.
__global__ __launch_bounds__(256, 2) void moe_gateup_kernel(
    const float* __restrict__ h2, const float* __restrict__ Wgu,
    const int* __restrict__ cnt, const int* __restrict__ lst_tok,
    const int* __restrict__ lst_pair, const float* __restrict__ pair_w,
    float* __restrict__ act) {
    int e = blockIdx.x;
    int n = cnt[e];
    int t0 = blockIdx.z * 128;
    if (t0 >= n) return;
    int i0 = blockIdx.y * 64;
    int tid = threadIdx.x;
    int tx = tid & 15, ty = tid >> 4;
    __shared__ __align__(16) float Hs[2][16][132];   // [k][token]
    __shared__ __align__(16) float Gs[2][16][68];    // [k][inter]
    __shared__ __align__(16) float Us[2][16][68];
    __shared__ int s_tok[128], s_pair[128];
    for (int i = tid; i < 128; i += 256) {
        bool ok = (t0 + i) < n;
        s_tok[i]  = ok ? lst_tok[e * T_TOK + t0 + i] : -1;
        s_pair[i] = ok ? lst_pair[e * T_TOK + t0 + i] : -1;
    }
    __syncthreads();

    // staging coords: H rows rH0 (0..63) and rH1 (64..127), k-offset kH
    int rH0 = tid >> 2, kH = (tid & 3) * 4;
    int rH1 = rH0 + 64;
    int tok0 = s_tok[rH0]; if (tok0 < 0) tok0 = 0;   // rows beyond n: load tok0's
    int tok1 = s_tok[rH1]; if (tok1 < 0) tok1 = 0;   // data, never stored
    int kG = tid >> 4, cG = (tid & 15) * 4;
    const float* W  = Wgu + (size_t)e * HID * (2 * INTER);
    const float* gp = W + (size_t)kG * (2 * INTER) + i0 + cG;
    const float* up = gp + INTER;
    const float* hp0 = h2 + (size_t)tok0 * HID + kH;
    const float* hp1 = h2 + (size_t)tok1 * HID + kH;

    float4 rh0, rh1, rg, ru;
    rh0 = *(const float4*)(hp0);
    rh1 = *(const float4*)(hp1);
    rg  = *(const float4*)(gp);
    ru  = *(const float4*)(up);
    Hs[0][kH + 0][rH0] = rh0.x; Hs[0][kH + 1][rH0] = rh0.y;
    Hs[0][kH + 2][rH0] = rh0.z; Hs[0][kH + 3][rH0] = rh0.w;
    Hs[0][kH + 0][rH1] = rh1.x; Hs[0][kH + 1][rH1] = rh1.y;
    Hs[0][kH + 2][rH1] = rh1.z; Hs[0][kH + 3][rH1] = rh1.w;
    *(float4*)&Gs[0][kG][cG] = rg;
    *(float4*)&Us[0][kG][cG] = ru;
    __syncthreads();

    float accg[8][4] = {}, accu[8][4] = {};
    const int NKt = HID / 16;  // 64
    for (int kt = 0; kt < NKt; ++kt) {
        int cur = kt & 1;
        bool more = (kt + 1 < NKt);
        if (more) {
            int k0 = (kt + 1) * 16;
            rh0 = *(const float4*)(hp0 + k0);
            rh1 = *(const float4*)(hp1 + k0);
            rg  = *(const float4*)(gp + (size_t)k0 * (2 * INTER));
            ru  = *(const float4*)(up + (size_t)k0 * (2 * INTER));
        }
#pragma unroll
        for (int kk = 0; kk < 16; ++kk) {
            float4 a0 = *(const float4*)&Hs[cur][kk][ty * 4];
            float4 a1 = *(const float4*)&Hs[cur][kk][64 + ty * 4];
            float4 g4 = *(const float4*)&Gs[cur][kk][tx * 4];
            float4 u4 = *(const float4*)&Us[cur][kk][tx * 4];
            float a[8] = {a0.x, a0.y, a0.z, a0.w, a1.x, a1.y, a1.z, a1.w};
            float gg[4] = {g4.x, g4.y, g4.z, g4.w};
            float uu[4] = {u4.x, u4.y, u4.z, u4.w};
#pragma unroll
            for (int i = 0; i < 8; ++i)
#pragma unroll
                for (int j = 0; j < 4; ++j) {
                    accg[i][j] += a[i] * gg[j];
                    accu[i][j] += a[i] * uu[j];
                }
        }
        __syncthreads();
        if (more) {
            int nb = cur ^ 1;
            Hs[nb][kH + 0][rH0] = rh0.x; Hs[nb][kH + 1][rH0] = rh0.y;
            Hs[nb][kH + 2][rH0] = rh0.z; Hs[nb][kH + 3][rH0] = rh0.w;
            Hs[nb][kH + 0][rH1] = rh1.x; Hs[nb][kH + 1][rH1] = rh1.y;
            Hs[nb][kH + 2][rH1] = rh1.z; Hs[nb][kH + 3][rH1] = rh1.w;
            *(float4*)&Gs[nb][kG][cG] = rg;
            *(float4*)&Us[nb][kG][cG] = ru;
        }
        __syncthreads();
    }

#pragma unroll
    for (int i = 0; i < 8; ++i) {
        int r = (i < 4) ? (ty * 4 + i) : (64 + ty * 4 + (i - 4));
        int pr = s_pair[r];
        if (pr < 0) continue;
        float w = pair_w[pr];
        float* ap = act + (size_t)pr * INTER + i0 + tx * 4;
        float4 o;
        float g, u;
        g = accg[i][0]; u = accu[i][0]; o.x = (g / (1.f + expf(-g))) * u * w;
        g = accg[i][1]; u = accu[i][1]; o.y = (g / (1.f + expf(-g))) * u * w;
        g = accg[i][2]; u = accu[i][2]; o.z = (g / (1.f + expf(-g))) * u * w;
        g = accg[i][3]; u = accu[i][3]; o.w = (g / (1.f + expf(-g))) * u * w;
        *(float4*)ap = o;
    }
}

// ---------------- MoE down: 128-token x 128-col tile, double-buffered ----------------
__global__ __launch_bounds__(256, 2) void moe_down_kernel(
    const float* __restrict__ act, const float* __restrict__ Wd,
    const int* __restrict__ cnt, const int* __restrict__ lst_tok,
    const int* __restrict__ lst_pair, float* __restrict__ acc_out) {
    int e = blockIdx.x;
    int n = cnt[e];
    int t0 = blockIdx.z * 128;
    if (t0 >= n) return;
    int c0 = blockIdx.y * 128;
    int tid = threadIdx.x;
    int tx = tid & 15, ty = tid >> 4;
    __shared__ __align__(16) float As[2][16][132];   // [k][token]
    __shared__ __align__(16) float Bs[2][16][132];   // [k][col]
    __shared__ int s_tok[128], s_pair[128];
    for (int i = tid; i < 128; i += 256) {
        bool ok = (t0 + i) < n;
        s_tok[i]  = ok ? lst_tok[e * T_TOK + t0 + i] : -1;
        s_pair[i] = ok ? lst_pair[e * T_TOK + t0 + i] : -1;
    }
    __syncthreads();

    int rA0 = tid >> 2, kA = (tid & 3) * 4;
    int rA1 = rA0 + 64;
    int pr0 = s_pair[rA0]; if (pr0 < 0) pr0 = 0;
    int pr1 = s_pair[rA1]; if (pr1 < 0) pr1 = 0;
    int kB = tid >> 5, cB = (tid & 31) * 4;
    const float* ap0 = act + (size_t)pr0 * INTER + kA;
    const float* ap1 = act + (size_t)pr1 * INTER + kA;
    const float* wp  = Wd + (size_t)e * INTER * HID + (size_t)kB * HID + c0 + cB;

    float4 ra0, ra1, rb0, rb1;
    ra0 = *(const float4*)(ap0);
    ra1 = *(const float4*)(ap1);
    rb0 = *(const float4*)(wp);
    rb1 = *(const float4*)(wp + (size_t)8 * HID);
    As[0][kA + 0][rA0] = ra0.x; As[0][kA + 1][rA0] = ra0.y;
    As[0][kA + 2][rA0] = ra0.z; As[0][kA + 3][rA0] = ra0.w;
    As[0][kA + 0][rA1] = ra1.x; As[0][kA + 1][rA1] = ra1.y;
    As[0][kA + 2][rA1] = ra1.z; As[0][kA + 3][rA1] = ra1.w;
    *(float4*)&Bs[0][kB][cB] = rb0;
    *(float4*)&Bs[0][kB + 8][cB] = rb1;
    __syncthreads();

    float acc[8][8] = {};
    const int NKt = INTER / 16;  // 32
    for (int kt = 0; kt < NKt; ++kt) {
        int cur = kt & 1;
        bool more = (kt + 1 < NKt);
        if (more) {
            int k0 = (kt + 1) * 16;
            ra0 = *(const float4*)(ap0 + k0);
            ra1 = *(const float4*)(ap1 + k0);
            rb0 = *(const float4*)(wp + (size_t)k0 * HID);
            rb1 = *(const float4*)(wp + (size_t)(k0 + 8) * HID);
        }
#pragma unroll
        for (int kk = 0; kk < 16; ++kk) {
            float4 a0 = *(const float4*)&As[cur][kk][ty * 4];
            float4 a1 = *(const float4*)&As[cur][kk][64 + ty * 4];
            float4 b0 = *(const float4*)&Bs[cur][kk][tx * 4];
            float4 b1 = *(const float4*)&Bs[cur][kk][64 + tx * 4];
            float a[8] = {a0.x, a0.y, a0.z, a0.w, a1.x, a1.y, a1.z, a1.w};
            float b[8] = {b0.x, b0.y, b0.z, b0.w, b1.x, b1.y, b1.z, b1.w};
#pragma unroll
            for (int i = 0; i < 8; ++i)
#pragma unroll
                for (int j = 0; j < 8; ++j) acc[i][j] += a[i] * b[j];
        }
        __syncthreads();
        if (more) {
            int nb = cur ^ 1;
            As[nb][kA + 0][rA0] = ra0.x; As[nb][kA + 1][rA0] = ra0.y;
            As[nb][kA + 2][rA0] = ra0.z; As[nb][kA + 3][rA0] = ra0.w;
            As[nb][kA + 0][rA1] = ra1.x; As[nb][kA + 1][rA1] = ra1.y;
            As[nb][kA + 2][rA1] = ra1.z; As[nb][kA + 3][rA1] = ra1.w;
            *(float4*)&Bs[nb][kB][cB] = rb0;
            *(float4*)&Bs[nb][kB + 8][cB] = rb1;
        }
        __syncthreads();
    }

#pragma unroll
    for (int i = 0; i < 8; ++i) {
        int r = (i < 4) ? (ty * 4 + i) : (64 + ty * 4 + (i - 4));
        int tok = s_tok[r];
        if (tok < 0) continue;
        float* op = acc_out + (size_t)tok * HID + c0;
#pragma unroll
        for (int j = 0; j < 8; ++j) {
            int c = (j < 4) ? (tx * 4 + j) : (64 + tx * 4 + (j - 4));
            atomicAdd(op + c, acc[i][j]);
        }
    }
}

// ---------------- final: out = x + moe ----------------
__global__ void final_add_kernel(const float* __restrict__ x, const float* __restrict__ moe,
                                 float* __restrict__ out) {
    int i = blockIdx.x * 256 + threadIdx.x;
    out[i] = x[i] + moe[i];
}

extern "C" void kernel_launch(void* const* d_in, const int* in_sizes, int n_in,
                              void* d_out, int out_size, void* d_ws, size_t ws_size,
                              hipStream_t stream) {
    const int*   positions = (const int*)d_in[0];
    const float* hidden    = (const float*)d_in[1];
    const float* Wqkv      = (const float*)d_in[2];
    const float* Wo        = (const float*)d_in[3];
    const float* q_norm_w  = (const float*)d_in[4];
    const float* k_norm_w  = (const float*)d_in[5];
    const float* in_ln_w   = (const float*)d_in[6];
    const float* post_ln_w = (const float*)d_in[7];
    const float* Wg        = (const float*)d_in[8];
    const float* Wgu       = (const float*)d_in[9];
    const float* Wd        = (const float*)d_in[10];
    float* out = (float*)d_out;

    char* ws = (char*)d_ws;
    size_t off = 0;
    auto alloc = [&](size_t bytes) { char* p = ws + off; off += (bytes + 255) & ~(size_t)255; return p; };
    float* bufA     = (float*)alloc((size_t)T_TOK * HID * 4);
    float* bufB     = (float*)alloc((size_t)T_TOK * 8 * INTER * 4);
    float* x        = (float*)alloc((size_t)T_TOK * HID * 4);
    float* acc_moe  = (float*)alloc((size_t)T_TOK * HID * 4);
    int*   cnt      = (int*)alloc(NE * 4);
    int*   lst_tok  = (int*)alloc((size_t)NE * T_TOK * 4);
    int*   lst_pair = (int*)alloc((size_t)NE * T_TOK * 4);
    float* pair_w   = (float*)alloc((size_t)T_TOK * 8 * 4);

    float* h        = bufA;
    float* attn_out = bufA;
    float* h2       = bufA;
    float* qkv      = bufB;
    float* act      = bufB;

    hipMemsetAsync(cnt, 0, NE * 4, stream);
    hipMemsetAsync(acc_moe, 0, (size_t)T_TOK * HID * 4, stream);

    rms_kernel<<<T_TOK, 256, 0, stream>>>(hidden, in_ln_w, h);
    gemm_f32<<<dim3(QKV_N / 128, T_TOK / 64), 256, 0, stream>>>(h, Wqkv, qkv, nullptr, T_TOK, QKV_N, HID);
    qk_rope_kernel<<<T_TOK * (NH + NKV), 64, 0, stream>>>(qkv, positions, q_norm_w, k_norm_w);
    attn_kernel<<<dim3(T_TOK, NH), 256, 0, stream>>>(qkv, attn_out);
    gemm_f32<<<dim3(HID / 128, T_TOK / 64), 256, 0, stream>>>(attn_out, Wo, x, hidden, T_TOK, HID, HID);
    rms_kernel<<<T_TOK, 256, 0, stream>>>(x, post_ln_w, h2);
    route_kernel<<<T_TOK, 64, 0, stream>>>(h2, Wg, cnt, lst_tok, lst_pair, pair_w);
    moe_gateup_kernel<<<dim3(NE, INTER / 64, T_TOK / 128), 256, 0, stream>>>(h2, Wgu, cnt, lst_tok, lst_pair, pair_w, act);
    moe_down_kernel<<<dim3(NE, HID / 128, T_TOK / 128), 256, 0, stream>>>(act, Wd, cnt, lst_tok, lst_pair, acc_moe);
    final_add_kernel<<<(T_TOK * HID) / 256, 256, 0, stream>>>(x, acc_moe, out);
}

// Round 2
// 1601.972 us; speedup vs baseline: 2.9477x; 2.9477x over previous
//
#include <hip/hip_runtime.h>

#define T_TOK 1024
#define HID 1024
#define NH 16
#define NKV 4
#define HDIM 64
#define NE 64
#define INTER 512
#define QKV_N 1536

// ---------------- RMSNorm (f32 input) ----------------
__global__ void rms_kernel(const float* __restrict__ x, const float* __restrict__ w,
                           float* __restrict__ out) {
    int t = blockIdx.x, tid = threadIdx.x;
    __shared__ float red[256];
    const float* xp = x + (size_t)t * HID;
    float v[4]; float ss = 0.f;
    for (int j = 0; j < 4; ++j) { v[j] = xp[tid * 4 + j]; ss += v[j] * v[j]; }
    red[tid] = ss; __syncthreads();
    for (int s = 128; s > 0; s >>= 1) { if (tid < s) red[tid] += red[tid + s]; __syncthreads(); }
    float r = rsqrtf(red[0] / (float)HID + 1e-6f);
    for (int j = 0; j < 4; ++j)
        out[(size_t)t * HID + tid * 4 + j] = v[j] * r * w[tid * 4 + j];
}

// ---------------- Dense GEMM: C(MxN) = A(MxK) @ B(KxN) [+ addend] ----------------
// 64x64 tile, 256 threads, 4x4 acc (known non-spilling), double-buffered LDS with
// register prefetch, ONE barrier per K-step.
__global__ __launch_bounds__(256) void gemm_f32(
    const float* __restrict__ A, const float* __restrict__ B,
    float* __restrict__ C, const float* __restrict__ addend,
    int M, int N, int K) {
    int row0 = blockIdx.y * 64, col0 = blockIdx.x * 64;
    int tid = threadIdx.x;
    int tx = tid & 15, ty = tid >> 4;
    __shared__ __align__(16) float As[2][16][68];   // [k][m]
    __shared__ __align__(16) float Bs[2][16][68];   // [k][n]

    int rA = tid >> 2, kA = (tid & 3) * 4;          // A: 64 rows x 4 k-offsets
    int kB = tid >> 4, cB = (tid & 15) * 4;         // B: 16 rows x 16 col-quads
    const float* pa = A + (size_t)(row0 + rA) * K + kA;
    const float* pb = B + (size_t)kB * N + col0 + cB;

    float4 ra = *(const float4*)(pa);
    float4 rb = *(const float4*)(pb);
    As[0][kA + 0][rA] = ra.x; As[0][kA + 1][rA] = ra.y;
    As[0][kA + 2][rA] = ra.z; As[0][kA + 3][rA] = ra.w;
    *(float4*)&Bs[0][kB][cB] = rb;
    __syncthreads();

    float acc[4][4] = {};
    int NKt = K / 16;
    for (int kt = 0; kt < NKt; ++kt) {
        int cur = kt & 1;
        bool more = (kt + 1 < NKt);
        if (more) {
            int k0 = (kt + 1) * 16;
            ra = *(const float4*)(pa + k0);
            rb = *(const float4*)(pb + (size_t)k0 * N);
        }
#pragma unroll
        for (int kk = 0; kk < 16; ++kk) {
            float4 av = *(const float4*)&As[cur][kk][ty * 4];
            float4 bv = *(const float4*)&Bs[cur][kk][tx * 4];
            float a[4] = {av.x, av.y, av.z, av.w};
            float b[4] = {bv.x, bv.y, bv.z, bv.w};
#pragma unroll
            for (int i = 0; i < 4; ++i)
#pragma unroll
                for (int j = 0; j < 4; ++j) acc[i][j] += a[i] * b[j];
        }
        if (more) {
            int nb = cur ^ 1;  // last read in kt-1; barrier at end of kt-1 ordered it
            As[nb][kA + 0][rA] = ra.x; As[nb][kA + 1][rA] = ra.y;
            As[nb][kA + 2][rA] = ra.z; As[nb][kA + 3][rA] = ra.w;
            *(float4*)&Bs[nb][kB][cB] = rb;
        }
        __syncthreads();
    }
#pragma unroll
    for (int i = 0; i < 4; ++i) {
        size_t r = row0 + ty * 4 + i;
        size_t c = col0 + tx * 4;
        float4 v = make_float4(acc[i][0], acc[i][1], acc[i][2], acc[i][3]);
        if (addend) {
            const float4 ad = *(const float4*)&addend[r * N + c];
            v.x += ad.x; v.y += ad.y; v.z += ad.z; v.w += ad.w;
        }
        *(float4*)&C[r * N + c] = v;
    }
}

// ---------------- per-head RMSNorm + RoPE on q,k (in-place in qkv f32) ----------------
__global__ void qk_rope_kernel(float* __restrict__ qkv, const int* __restrict__ pos,
                               const float* __restrict__ qw, const float* __restrict__ kw) {
    int b = blockIdx.x;
    int t = b / (NH + NKV), hh = b % (NH + NKV);
    int lane = threadIdx.x;
    bool isq = hh < NH;
    int off = isq ? hh * HDIM : NH * HDIM + (hh - NH) * HDIM;
    const float* w = isq ? qw : kw;
    float* p = qkv + (size_t)t * QKV_N + off;
    float x = p[lane];
    float ss = x * x;
    for (int m = 1; m < 64; m <<= 1) ss += __shfl_xor(ss, m, 64);
    float r = rsqrtf(ss / (float)HDIM + 1e-6f);
    x = x * r * w[lane];
    float partner = __shfl_xor(x, 32, 64);
    int i = lane & 31;
    float freq = expf(-(float)i * (9.21034037198f / 32.f));  // 10000^(-i/32)
    float f = (float)pos[t] * freq;
    float c = cosf(f), s = sinf(f);
    float outv = (lane < 32) ? (x * c - partner * s) : (x * c + partner * s);
    p[lane] = outv;
}

// ---------------- attention: one block per (t, head) ----------------
__global__ void attn_kernel(const float* __restrict__ qkv, float* __restrict__ attn_out) {
    int t = blockIdx.x, hh = blockIdx.y;
    int kh = hh >> 2;
    __shared__ float sq[64];
    __shared__ float sc[T_TOK];
    __shared__ float red[256];
    __shared__ float po[4][64];
    int tid = threadIdx.x;
    const float* qp = qkv + (size_t)t * QKV_N + hh * HDIM;
    if (tid < 64) sq[tid] = qp[tid];
    __syncthreads();
    int L = t + 1;
    float lmax = -1e30f;
    for (int s = tid; s < L; s += 256) {
        const float* kp = qkv + (size_t)s * QKV_N + NH * HDIM + kh * HDIM;
        float dot = 0.f;
        for (int d = 0; d < 64; ++d) dot += sq[d] * kp[d];
        dot *= 0.125f;  // 1/sqrt(64)
        sc[s] = dot;
        lmax = fmaxf(lmax, dot);
    }
    red[tid] = lmax; __syncthreads();
    for (int s = 128; s > 0; s >>= 1) { if (tid < s) red[tid] = fmaxf(red[tid], red[tid + s]); __syncthreads(); }
    float mx = red[0]; __syncthreads();
    float lsum = 0.f;
    for (int s = tid; s < L; s += 256) { float e = expf(sc[s] - mx); sc[s] = e; lsum += e; }
    red[tid] = lsum; __syncthreads();
    for (int s = 128; s > 0; s >>= 1) { if (tid < s) red[tid] += red[tid + s]; __syncthreads(); }
    float inv = 1.f / red[0];
    int grp = tid >> 6, lane = tid & 63;
    float acc = 0.f;
    for (int s = grp; s < L; s += 4)
        acc += sc[s] * qkv[(size_t)s * QKV_N + (NH + NKV) * HDIM + kh * HDIM + lane];
    po[grp][lane] = acc;
    __syncthreads();
    if (tid < 64) {
        float o = (po[0][tid] + po[1][tid] + po[2][tid] + po[3][tid]) * inv;
        attn_out[(size_t)t * HID + hh * HDIM + tid] = o;
    }
}

// ---------------- router: logits, softmax, group top-1, scatter ----------------
__global__ void route_kernel(const float* __restrict__ h2, const float* __restrict__ Wg,
                             int* __restrict__ cnt, int* __restrict__ lst_tok,
                             int* __restrict__ lst_pair, float* __restrict__ pair_w) {
    int t = blockIdx.x, j = threadIdx.x;  // 64 threads
    const float* hp = h2 + (size_t)t * HID;
    float acc = 0.f;
    for (int k = 0; k < HID; ++k) acc += hp[k] * Wg[(size_t)k * NE + j];
    float mx = acc;
    for (int m = 1; m < 64; m <<= 1) mx = fmaxf(mx, __shfl_xor(mx, m, 64));
    float e = expf(acc - mx);
    float sm = e;
    for (int m = 1; m < 64; m <<= 1) sm += __shfl_xor(sm, m, 64);
    float p = e / sm;
    float bp = p; int bi = j;
    for (int m = 1; m < 8; m <<= 1) {
        float op = __shfl_xor(bp, m, 64);
        int oi = __shfl_xor(bi, m, 64);
        if (op > bp || (op == bp && oi < bi)) { bp = op; bi = oi; }
    }
    __shared__ float gw[8]; __shared__ int gi[8];
    if ((j & 7) == 0) { gw[j >> 3] = bp; gi[j >> 3] = bi; }
    __syncthreads();
    if (j < 8) {
        float tw = gw[j];
        float wsum = tw;
        for (int m = 1; m < 8; m <<= 1) wsum += __shfl_xor(wsum, m, 64);
        float w = tw / wsum;
        int ei = gi[j];
        int pos = atomicAdd(&cnt[ei], 1);
        lst_tok[ei * T_TOK + pos] = t;
        lst_pair[ei * T_TOK + pos] = t * 8 + j;
        pair_w[t * 8 + j] = w;
    }
}

// ---------------- MoE gate_up + SiLU*up*w ----------------
// 64-token x 64-inter tile, z-split over 64-token tiles, double-buffered LDS,
// 4x4 + 4x4 acc per thread (round-0 non-spilling budget).
__global__ __launch_bounds__(256) void moe_gateup_kernel(
    const float* __restrict__ h2, const float* __restrict__ Wgu,
    const int* __restrict__ cnt, const int* __restrict__ lst_tok,
    const int* __restrict__ lst_pair, const float* __restrict__ pair_w,
    float* __restrict__ act) {
    int e = blockIdx.x;
    int n = cnt[e];
    int t0 = blockIdx.z * 64;
    if (t0 >= n) return;
    int i0 = blockIdx.y * 64;
    int tid = threadIdx.x;
    int tx = tid & 15, ty = tid >> 4;
    __shared__ __align__(16) float Hs[2][16][68];   // [k][token]
    __shared__ __align__(16) float Gs[2][16][68];   // [k][inter]
    __shared__ __align__(16) float Us[2][16][68];
    __shared__ int s_tok[64], s_pair[64];
    if (tid < 64) {
        bool ok = (t0 + tid) < n;
        s_tok[tid]  = ok ? lst_tok[e * T_TOK + t0 + tid] : -1;
        s_pair[tid] = ok ? lst_pair[e * T_TOK + t0 + tid] : -1;
    }
    __syncthreads();

    int rH = tid >> 2, kH = (tid & 3) * 4;
    int tok = s_tok[rH]; if (tok < 0) tok = 0;      // clamped rows never stored
    int kG = tid >> 4, cG = (tid & 15) * 4;
    const float* W  = Wgu + (size_t)e * HID * (2 * INTER);
    const float* gp = W + (size_t)kG * (2 * INTER) + i0 + cG;
    const float* up = gp + INTER;
    const float* hp = h2 + (size_t)tok * HID + kH;

    float4 rh = *(const float4*)(hp);
    float4 rg = *(const float4*)(gp);
    float4 ru = *(const float4*)(up);
    Hs[0][kH + 0][rH] = rh.x; Hs[0][kH + 1][rH] = rh.y;
    Hs[0][kH + 2][rH] = rh.z; Hs[0][kH + 3][rH] = rh.w;
    *(float4*)&Gs[0][kG][cG] = rg;
    *(float4*)&Us[0][kG][cG] = ru;
    __syncthreads();

    float accg[4][4] = {}, accu[4][4] = {};
    const int NKt = HID / 16;  // 64
    for (int kt = 0; kt < NKt; ++kt) {
        int cur = kt & 1;
        bool more = (kt + 1 < NKt);
        if (more) {
            int k0 = (kt + 1) * 16;
            rh = *(const float4*)(hp + k0);
            rg = *(const float4*)(gp + (size_t)k0 * (2 * INTER));
            ru = *(const float4*)(up + (size_t)k0 * (2 * INTER));
        }
#pragma unroll
        for (int kk = 0; kk < 16; ++kk) {
            float4 av = *(const float4*)&Hs[cur][kk][ty * 4];
            float4 g4 = *(const float4*)&Gs[cur][kk][tx * 4];
            float4 u4 = *(const float4*)&Us[cur][kk][tx * 4];
            float a[4] = {av.x, av.y, av.z, av.w};
            float gg[4] = {g4.x, g4.y, g4.z, g4.w};
            float uu[4] = {u4.x, u4.y, u4.z, u4.w};
#pragma unroll
            for (int i = 0; i < 4; ++i)
#pragma unroll
                for (int j = 0; j < 4; ++j) {
                    accg[i][j] += a[i] * gg[j];
                    accu[i][j] += a[i] * uu[j];
                }
        }
        if (more) {
            int nb = cur ^ 1;
            Hs[nb][kH + 0][rH] = rh.x; Hs[nb][kH + 1][rH] = rh.y;
            Hs[nb][kH + 2][rH] = rh.z; Hs[nb][kH + 3][rH] = rh.w;
            *(float4*)&Gs[nb][kG][cG] = rg;
            *(float4*)&Us[nb][kG][cG] = ru;
        }
        __syncthreads();
    }

#pragma unroll
    for (int i = 0; i < 4; ++i) {
        int r = ty * 4 + i;
        int pr = s_pair[r];
        if (pr < 0) continue;
        float w = pair_w[pr];
        float* ap = act + (size_t)pr * INTER + i0 + tx * 4;
        float4 o;
        float g, u;
        g = accg[i][0]; u = accu[i][0]; o.x = (g / (1.f + expf(-g))) * u * w;
        g = accg[i][1]; u = accu[i][1]; o.y = (g / (1.f + expf(-g))) * u * w;
        g = accg[i][2]; u = accu[i][2]; o.z = (g / (1.f + expf(-g))) * u * w;
        g = accg[i][3]; u = accu[i][3]; o.w = (g / (1.f + expf(-g))) * u * w;
        *(float4*)ap = o;
    }
}

// ---------------- MoE down: 64-token x 64-col tile, double-buffered, z-split ----------------
__global__ __launch_bounds__(256) void moe_down_kernel(
    const float* __restrict__ act, const float* __restrict__ Wd,
    const int* __restrict__ cnt, const int* __restrict__ lst_tok,
    const int* __restrict__ lst_pair, float* __restrict__ acc_out) {
    int e = blockIdx.x;
    int n = cnt[e];
    int t0 = blockIdx.z * 64;
    if (t0 >= n) return;
    int c0 = blockIdx.y * 64;
    int tid = threadIdx.x;
    int tx = tid & 15, ty = tid >> 4;
    __shared__ __align__(16) float As[2][16][68];   // [k][token]
    __shared__ __align__(16) float Ws[2][16][68];   // [k][col]
    __shared__ int s_tok[64], s_pair[64];
    if (tid < 64) {
        bool ok = (t0 + tid) < n;
        s_tok[tid]  = ok ? lst_tok[e * T_TOK + t0 + tid] : -1;
        s_pair[tid] = ok ? lst_pair[e * T_TOK + t0 + tid] : -1;
    }
    __syncthreads();

    int rA = tid >> 2, kA = (tid & 3) * 4;
    int pr = s_pair[rA]; if (pr < 0) pr = 0;
    int kB = tid >> 4, cB = (tid & 15) * 4;
    const float* ap = act + (size_t)pr * INTER + kA;
    const float* wp = Wd + (size_t)e * INTER * HID + (size_t)kB * HID + c0 + cB;

    float4 ra = *(const float4*)(ap);
    float4 rb = *(const float4*)(wp);
    As[0][kA + 0][rA] = ra.x; As[0][kA + 1][rA] = ra.y;
    As[0][kA + 2][rA] = ra.z; As[0][kA + 3][rA] = ra.w;
    *(float4*)&Ws[0][kB][cB] = rb;
    __syncthreads();

    float acc[4][4] = {};
    const int NKt = INTER / 16;  // 32
    for (int kt = 0; kt < NKt; ++kt) {
        int cur = kt & 1;
        bool more = (kt + 1 < NKt);
        if (more) {
            int k0 = (kt + 1) * 16;
            ra = *(const float4*)(ap + k0);
            rb = *(const float4*)(wp + (size_t)k0 * HID);
        }
#pragma unroll
        for (int kk = 0; kk < 16; ++kk) {
            float4 av = *(const float4*)&As[cur][kk][ty * 4];
            float4 bv = *(const float4*)&Ws[cur][kk][tx * 4];
            float a[4] = {av.x, av.y, av.z, av.w};
            float b[4] = {bv.x, bv.y, bv.z, bv.w};
#pragma unroll
            for (int i = 0; i < 4; ++i)
#pragma unroll
                for (int j = 0; j < 4; ++j) acc[i][j] += a[i] * b[j];
        }
        if (more) {
            int nb = cur ^ 1;
            As[nb][kA + 0][rA] = ra.x; As[nb][kA + 1][rA] = ra.y;
            As[nb][kA + 2][rA] = ra.z; As[nb][kA + 3][rA] = ra.w;
            *(float4*)&Ws[nb][kB][cB] = rb;
        }
        __syncthreads();
    }

#pragma unroll
    for (int i = 0; i < 4; ++i) {
        int r = ty * 4 + i;
        int tok = s_tok[r];
        if (tok < 0) continue;
        float* op = acc_out + (size_t)tok * HID + c0 + tx * 4;
#pragma unroll
        for (int j = 0; j < 4; ++j)
            atomicAdd(op + j, acc[i][j]);
    }
}

// ---------------- final: out = x + moe ----------------
__global__ void final_add_kernel(const float* __restrict__ x, const float* __restrict__ moe,
                                 float* __restrict__ out) {
    int i = blockIdx.x * 256 + threadIdx.x;
    out[i] = x[i] + moe[i];
}

extern "C" void kernel_launch(void* const* d_in, const int* in_sizes, int n_in,
                              void* d_out, int out_size, void* d_ws, size_t ws_size,
                              hipStream_t stream) {
    const int*   positions = (const int*)d_in[0];
    const float* hidden    = (const float*)d_in[1];
    const float* Wqkv      = (const float*)d_in[2];
    const float* Wo        = (const float*)d_in[3];
    const float* q_norm_w  = (const float*)d_in[4];
    const float* k_norm_w  = (const float*)d_in[5];
    const float* in_ln_w   = (const float*)d_in[6];
    const float* post_ln_w = (const float*)d_in[7];
    const float* Wg        = (const float*)d_in[8];
    const float* Wgu       = (const float*)d_in[9];
    const float* Wd        = (const float*)d_in[10];
    float* out = (float*)d_out;

    char* ws = (char*)d_ws;
    size_t off = 0;
    auto alloc = [&](size_t bytes) { char* p = ws + off; off += (bytes + 255) & ~(size_t)255; return p; };
    float* bufA     = (float*)alloc((size_t)T_TOK * HID * 4);
    float* bufB     = (float*)alloc((size_t)T_TOK * 8 * INTER * 4);
    float* x        = (float*)alloc((size_t)T_TOK * HID * 4);
    float* acc_moe  = (float*)alloc((size_t)T_TOK * HID * 4);
    int*   cnt      = (int*)alloc(NE * 4);
    int*   lst_tok  = (int*)alloc((size_t)NE * T_TOK * 4);
    int*   lst_pair = (int*)alloc((size_t)NE * T_TOK * 4);
    float* pair_w   = (float*)alloc((size_t)T_TOK * 8 * 4);

    float* h        = bufA;
    float* attn_out = bufA;
    float* h2       = bufA;
    float* qkv      = bufB;
    float* act      = bufB;

    hipMemsetAsync(cnt, 0, NE * 4, stream);
    hipMemsetAsync(acc_moe, 0, (size_t)T_TOK * HID * 4, stream);

    rms_kernel<<<T_TOK, 256, 0, stream>>>(hidden, in_ln_w, h);
    gemm_f32<<<dim3(QKV_N / 64, T_TOK / 64), 256, 0, stream>>>(h, Wqkv, qkv, nullptr, T_TOK, QKV_N, HID);
    qk_rope_kernel<<<T_TOK * (NH + NKV), 64, 0, stream>>>(qkv, positions, q_norm_w, k_norm_w);
    attn_kernel<<<dim3(T_TOK, NH), 256, 0, stream>>>(qkv, attn_out);
    gemm_f32<<<dim3(HID / 64, T_TOK / 64), 256, 0, stream>>>(attn_out, Wo, x, hidden, T_TOK, HID, HID);
    rms_kernel<<<T_TOK, 256, 0, stream>>>(x, post_ln_w, h2);
    route_kernel<<<T_TOK, 64, 0, stream>>>(h2, Wg, cnt, lst_tok, lst_pair, pair_w);
    moe_gateup_kernel<<<dim3(NE, INTER / 64, T_TOK / 64), 256, 0, stream>>>(h2, Wgu, cnt, lst_tok, lst_pair, pair_w, act);
    moe_down_kernel<<<dim3(NE, HID / 64, T_TOK / 64), 256, 0, stream>>>(act, Wd, cnt, lst_tok, lst_pair, acc_moe);
    final_add_kernel<<<(T_TOK * HID) / 256, 256, 0, stream>>>(x, acc_moe, out);
}

// Round 4
// 1197.807 us; speedup vs baseline: 3.9423x; 1.3374x over previous
//
#include <hip/hip_runtime.h>

#define T_TOK 1024
#define HID 1024
#define NH 16
#define NKV 4
#define HDIM 64
#define NE 64
#define INTER 512
#define QKV_N 1536

// ---------------- RMSNorm (f32 input) ----------------
__global__ void rms_kernel(const float* __restrict__ x, const float* __restrict__ w,
                           float* __restrict__ out) {
    int t = blockIdx.x, tid = threadIdx.x;
    __shared__ float red[256];
    const float* xp = x + (size_t)t * HID;
    float v[4]; float ss = 0.f;
    for (int j = 0; j < 4; ++j) { v[j] = xp[tid * 4 + j]; ss += v[j] * v[j]; }
    red[tid] = ss; __syncthreads();
    for (int s = 128; s > 0; s >>= 1) { if (tid < s) red[tid] += red[tid + s]; __syncthreads(); }
    float r = rsqrtf(red[0] / (float)HID + 1e-6f);
    for (int j = 0; j < 4; ++j)
        out[(size_t)t * HID + tid * 4 + j] = v[j] * r * w[tid * 4 + j];
}

// ---------------- Dense GEMM: C(MxN) = A(MxK) @ B(KxN) [+ addend] ----------------
__global__ __launch_bounds__(256) void gemm_f32(
    const float* __restrict__ A, const float* __restrict__ B,
    float* __restrict__ C, const float* __restrict__ addend,
    int M, int N, int K) {
    int row0 = blockIdx.y * 64, col0 = blockIdx.x * 64;
    int tid = threadIdx.x;
    int tx = tid & 15, ty = tid >> 4;
    __shared__ __align__(16) float As[2][16][68];   // [k][m]
    __shared__ __align__(16) float Bs[2][16][68];   // [k][n]

    int rA = tid >> 2, kA = (tid & 3) * 4;
    int kB = tid >> 4, cB = (tid & 15) * 4;
    const float* pa = A + (size_t)(row0 + rA) * K + kA;
    const float* pb = B + (size_t)kB * N + col0 + cB;

    float4 ra = *(const float4*)(pa);
    float4 rb = *(const float4*)(pb);
    As[0][kA + 0][rA] = ra.x; As[0][kA + 1][rA] = ra.y;
    As[0][kA + 2][rA] = ra.z; As[0][kA + 3][rA] = ra.w;
    *(float4*)&Bs[0][kB][cB] = rb;
    __syncthreads();

    float acc[4][4] = {};
    int NKt = K / 16;
    for (int kt = 0; kt < NKt; ++kt) {
        int cur = kt & 1;
        bool more = (kt + 1 < NKt);
        if (more) {
            int k0 = (kt + 1) * 16;
            ra = *(const float4*)(pa + k0);
            rb = *(const float4*)(pb + (size_t)k0 * N);
        }
#pragma unroll
        for (int kk = 0; kk < 16; ++kk) {
            float4 av = *(const float4*)&As[cur][kk][ty * 4];
            float4 bv = *(const float4*)&Bs[cur][kk][tx * 4];
            float a[4] = {av.x, av.y, av.z, av.w};
            float b[4] = {bv.x, bv.y, bv.z, bv.w};
#pragma unroll
            for (int i = 0; i < 4; ++i)
#pragma unroll
                for (int j = 0; j < 4; ++j) acc[i][j] += a[i] * b[j];
        }
        if (more) {
            int nb = cur ^ 1;
            As[nb][kA + 0][rA] = ra.x; As[nb][kA + 1][rA] = ra.y;
            As[nb][kA + 2][rA] = ra.z; As[nb][kA + 3][rA] = ra.w;
            *(float4*)&Bs[nb][kB][cB] = rb;
        }
        __syncthreads();
    }
#pragma unroll
    for (int i = 0; i < 4; ++i) {
        size_t r = row0 + ty * 4 + i;
        size_t c = col0 + tx * 4;
        float4 v = make_float4(acc[i][0], acc[i][1], acc[i][2], acc[i][3]);
        if (addend) {
            const float4 ad = *(const float4*)&addend[r * N + c];
            v.x += ad.x; v.y += ad.y; v.z += ad.z; v.w += ad.w;
        }
        *(float4*)&C[r * N + c] = v;
    }
}

// ---------------- per-head RMSNorm + RoPE on q,k (in-place in qkv f32) ----------------
__global__ void qk_rope_kernel(float* __restrict__ qkv, const int* __restrict__ pos,
                               const float* __restrict__ qw, const float* __restrict__ kw) {
    int b = blockIdx.x;
    int t = b / (NH + NKV), hh = b % (NH + NKV);
    int lane = threadIdx.x;
    bool isq = hh < NH;
    int off = isq ? hh * HDIM : NH * HDIM + (hh - NH) * HDIM;
    const float* w = isq ? qw : kw;
    float* p = qkv + (size_t)t * QKV_N + off;
    float x = p[lane];
    float ss = x * x;
    for (int m = 1; m < 64; m <<= 1) ss += __shfl_xor(ss, m, 64);
    float r = rsqrtf(ss / (float)HDIM + 1e-6f);
    x = x * r * w[lane];
    float partner = __shfl_xor(x, 32, 64);
    int i = lane & 31;
    float freq = expf(-(float)i * (9.21034037198f / 32.f));  // 10000^(-i/32)
    float f = (float)pos[t] * freq;
    float c = cosf(f), s = sinf(f);
    float outv = (lane < 32) ? (x * c - partner * s) : (x * c + partner * s);
    p[lane] = outv;
}

// ---------------- flash attention: one block per (head, 64-query tile) ----------------
// Per k-tile: stage K^T,V in LDS; 4x4-reg QK^T; in-wave shfl online softmax;
// P through the (reused) K buffer; 4x4-reg PV with running rescale.
// Each thread stages 4 float4 = 16 dims of its row (full 64x64 tile).
__global__ __launch_bounds__(256) void flash_attn_kernel(
    const float* __restrict__ qkv, float* __restrict__ attn_out) {
    int h = blockIdx.x;            // 16 heads
    int qt = 15 - blockIdx.y;      // 16 q-tiles, long blocks dispatched first
    int kh = h >> 2;
    int tid = threadIdx.x;
    int tx = tid & 15, ty = tid >> 4;

    __shared__ __align__(16) float Qs[64][68];    // [d][q]     17.4 KB
    __shared__ __align__(16) float KPs[64][68];   // K^T: [d][kv] then P: [kv][q]
    __shared__ __align__(16) float Vs[64][68];    // [kv][d]
    // total 52.2 KB

    int r = tid >> 2;              // row 0..63
    int c0 = (tid & 3) * 4;        // dim base {0,4,8,12}; full dims = c0 + cc*16

    // stage Q^T once (RoPE'd q values): all 64 dims
    {
        const float* qp = qkv + (size_t)(qt * 64 + r) * QKV_N + h * HDIM;
#pragma unroll
        for (int cc = 0; cc < 4; ++cc) {
            int d = c0 + cc * 16;
            float4 fq = *(const float4*)(qp + d);
            Qs[d + 0][r] = fq.x; Qs[d + 1][r] = fq.y;
            Qs[d + 2][r] = fq.z; Qs[d + 3][r] = fq.w;
        }
    }

    const float* kp = qkv + (size_t)r * QKV_N + NH * HDIM + kh * HDIM;
    const float* vp = qkv + (size_t)r * QKV_N + (NH + NKV) * HDIM + kh * HDIM;

    float m[4], l[4], accO[4][4] = {};
#pragma unroll
    for (int i = 0; i < 4; ++i) { m[i] = -1e30f; l[i] = 0.f; }

    for (int kt = 0; kt <= qt; ++kt) {
        // issue K/V loads for this tile (overlap with barrier wait)
        size_t toff = (size_t)kt * 64 * QKV_N;
        float4 fk[4], fv[4];
#pragma unroll
        for (int cc = 0; cc < 4; ++cc) {
            fk[cc] = *(const float4*)(kp + toff + c0 + cc * 16);
            fv[cc] = *(const float4*)(vp + toff + c0 + cc * 16);
        }
        __syncthreads();   // A: prev GEMM2 done reading KPs(P)/Vs
#pragma unroll
        for (int cc = 0; cc < 4; ++cc) {
            int d = c0 + cc * 16;
            KPs[d + 0][r] = fk[cc].x; KPs[d + 1][r] = fk[cc].y;
            KPs[d + 2][r] = fk[cc].z; KPs[d + 3][r] = fk[cc].w;
            *(float4*)&Vs[r][d] = fv[cc];
        }
        __syncthreads();   // B: K,V staged

        // GEMM1: S = Q @ K^T  (reduce over 64 head dims)
        float s[4][4] = {};
#pragma unroll 16
        for (int kk = 0; kk < 64; ++kk) {
            float4 qa = *(const float4*)&Qs[kk][ty * 4];
            float4 kb = *(const float4*)&KPs[kk][tx * 4];
            float a[4] = {qa.x, qa.y, qa.z, qa.w};
            float b[4] = {kb.x, kb.y, kb.z, kb.w};
#pragma unroll
            for (int i = 0; i < 4; ++i)
#pragma unroll
                for (int j = 0; j < 4; ++j) s[i][j] += a[i] * b[j];
        }
#pragma unroll
        for (int i = 0; i < 4; ++i)
#pragma unroll
            for (int j = 0; j < 4; ++j) s[i][j] *= 0.125f;   // 1/sqrt(64)

        if (kt == qt) {   // causal mask on diagonal tile
#pragma unroll
            for (int i = 0; i < 4; ++i)
#pragma unroll
                for (int j = 0; j < 4; ++j)
                    if (tx * 4 + j > ty * 4 + i) s[i][j] = -1e30f;
        }

        // online softmax: each q-row lives in one 16-lane group (fixed ty)
#pragma unroll
        for (int i = 0; i < 4; ++i) {
            float rm = fmaxf(fmaxf(s[i][0], s[i][1]), fmaxf(s[i][2], s[i][3]));
            rm = fmaxf(rm, __shfl_xor(rm, 1, 64));
            rm = fmaxf(rm, __shfl_xor(rm, 2, 64));
            rm = fmaxf(rm, __shfl_xor(rm, 4, 64));
            rm = fmaxf(rm, __shfl_xor(rm, 8, 64));
            float mn = fmaxf(m[i], rm);
            float sc = __expf(m[i] - mn);
            float ps = 0.f;
#pragma unroll
            for (int j = 0; j < 4; ++j) {
                float p = __expf(s[i][j] - mn);
                s[i][j] = p; ps += p;
            }
            ps += __shfl_xor(ps, 1, 64);
            ps += __shfl_xor(ps, 2, 64);
            ps += __shfl_xor(ps, 4, 64);
            ps += __shfl_xor(ps, 8, 64);
            l[i] = l[i] * sc + ps;
            m[i] = mn;
#pragma unroll
            for (int j = 0; j < 4; ++j) accO[i][j] *= sc;
        }

        __syncthreads();   // C1: all waves done reading KPs as K
        // P -> KPs transposed: P[kv][q]
#pragma unroll
        for (int i = 0; i < 4; ++i)
#pragma unroll
            for (int j = 0; j < 4; ++j)
                KPs[tx * 4 + j][ty * 4 + i] = s[i][j];
        __syncthreads();   // C2: P staged

        // GEMM2: O += P @ V  (reduce over 64 kv slots)
#pragma unroll 16
        for (int kk = 0; kk < 64; ++kk) {
            float4 pa = *(const float4*)&KPs[kk][ty * 4];
            float4 vb = *(const float4*)&Vs[kk][tx * 4];
            float a[4] = {pa.x, pa.y, pa.z, pa.w};
            float b[4] = {vb.x, vb.y, vb.z, vb.w};
#pragma unroll
            for (int i = 0; i < 4; ++i)
#pragma unroll
                for (int j = 0; j < 4; ++j) accO[i][j] += a[i] * b[j];
        }
    }

    // epilogue: normalize and store
#pragma unroll
    for (int i = 0; i < 4; ++i) {
        float inv = 1.f / l[i];
        int row = qt * 64 + ty * 4 + i;
        float4 o = make_float4(accO[i][0] * inv, accO[i][1] * inv,
                               accO[i][2] * inv, accO[i][3] * inv);
        *(float4*)&attn_out[(size_t)row * HID + h * HDIM + tx * 4] = o;
    }
}

// ---------------- router: logits, softmax, group top-1, scatter ----------------
__global__ void route_kernel(const float* __restrict__ h2, const float* __restrict__ Wg,
                             int* __restrict__ cnt, int* __restrict__ lst_tok,
                             int* __restrict__ lst_pair, float* __restrict__ pair_w) {
    int t = blockIdx.x, j = threadIdx.x;  // 64 threads
    const float* hp = h2 + (size_t)t * HID;
    float acc = 0.f;
    for (int k = 0; k < HID; ++k) acc += hp[k] * Wg[(size_t)k * NE + j];
    float mx = acc;
    for (int m = 1; m < 64; m <<= 1) mx = fmaxf(mx, __shfl_xor(mx, m, 64));
    float e = expf(acc - mx);
    float sm = e;
    for (int m = 1; m < 64; m <<= 1) sm += __shfl_xor(sm, m, 64);
    float p = e / sm;
    float bp = p; int bi = j;
    for (int m = 1; m < 8; m <<= 1) {
        float op = __shfl_xor(bp, m, 64);
        int oi = __shfl_xor(bi, m, 64);
        if (op > bp || (op == bp && oi < bi)) { bp = op; bi = oi; }
    }
    __shared__ float gw[8]; __shared__ int gi[8];
    if ((j & 7) == 0) { gw[j >> 3] = bp; gi[j >> 3] = bi; }
    __syncthreads();
    if (j < 8) {
        float tw = gw[j];
        float wsum = tw;
        for (int m = 1; m < 8; m <<= 1) wsum += __shfl_xor(wsum, m, 64);
        float w = tw / wsum;
        int ei = gi[j];
        int pos = atomicAdd(&cnt[ei], 1);
        lst_tok[ei * T_TOK + pos] = t;
        lst_pair[ei * T_TOK + pos] = t * 8 + j;
        pair_w[t * 8 + j] = w;
    }
}

// ---------------- MoE gate_up + SiLU*up*w ----------------
__global__ __launch_bounds__(256) void moe_gateup_kernel(
    const float* __restrict__ h2, const float* __restrict__ Wgu,
    const int* __restrict__ cnt, const int* __restrict__ lst_tok,
    const int* __restrict__ lst_pair, const float* __restrict__ pair_w,
    float* __restrict__ act) {
    int e = blockIdx.x;
    int n = cnt[e];
    int t0 = blockIdx.z * 64;
    if (t0 >= n) return;
    int i0 = blockIdx.y * 64;
    int tid = threadIdx.x;
    int tx = tid & 15, ty = tid >> 4;
    __shared__ __align__(16) float Hs[2][16][68];
    __shared__ __align__(16) float Gs[2][16][68];
    __shared__ __align__(16) float Us[2][16][68];
    __shared__ int s_tok[64], s_pair[64];
    if (tid < 64) {
        bool ok = (t0 + tid) < n;
        s_tok[tid]  = ok ? lst_tok[e * T_TOK + t0 + tid] : -1;
        s_pair[tid] = ok ? lst_pair[e * T_TOK + t0 + tid] : -1;
    }
    __syncthreads();

    int rH = tid >> 2, kH = (tid & 3) * 4;
    int tok = s_tok[rH]; if (tok < 0) tok = 0;
    int kG = tid >> 4, cG = (tid & 15) * 4;
    const float* W  = Wgu + (size_t)e * HID * (2 * INTER);
    const float* gp = W + (size_t)kG * (2 * INTER) + i0 + cG;
    const float* up = gp + INTER;
    const float* hp = h2 + (size_t)tok * HID + kH;

    float4 rh = *(const float4*)(hp);
    float4 rg = *(const float4*)(gp);
    float4 ru = *(const float4*)(up);
    Hs[0][kH + 0][rH] = rh.x; Hs[0][kH + 1][rH] = rh.y;
    Hs[0][kH + 2][rH] = rh.z; Hs[0][kH + 3][rH] = rh.w;
    *(float4*)&Gs[0][kG][cG] = rg;
    *(float4*)&Us[0][kG][cG] = ru;
    __syncthreads();

    float accg[4][4] = {}, accu[4][4] = {};
    const int NKt = HID / 16;
    for (int kt = 0; kt < NKt; ++kt) {
        int cur = kt & 1;
        bool more = (kt + 1 < NKt);
        if (more) {
            int k0 = (kt + 1) * 16;
            rh = *(const float4*)(hp + k0);
            rg = *(const float4*)(gp + (size_t)k0 * (2 * INTER));
            ru = *(const float4*)(up + (size_t)k0 * (2 * INTER));
        }
#pragma unroll
        for (int kk = 0; kk < 16; ++kk) {
            float4 av = *(const float4*)&Hs[cur][kk][ty * 4];
            float4 g4 = *(const float4*)&Gs[cur][kk][tx * 4];
            float4 u4 = *(const float4*)&Us[cur][kk][tx * 4];
            float a[4] = {av.x, av.y, av.z, av.w};
            float gg[4] = {g4.x, g4.y, g4.z, g4.w};
            float uu[4] = {u4.x, u4.y, u4.z, u4.w};
#pragma unroll
            for (int i = 0; i < 4; ++i)
#pragma unroll
                for (int j = 0; j < 4; ++j) {
                    accg[i][j] += a[i] * gg[j];
                    accu[i][j] += a[i] * uu[j];
                }
        }
        if (more) {
            int nb = cur ^ 1;
            Hs[nb][kH + 0][rH] = rh.x; Hs[nb][kH + 1][rH] = rh.y;
            Hs[nb][kH + 2][rH] = rh.z; Hs[nb][kH + 3][rH] = rh.w;
            *(float4*)&Gs[nb][kG][cG] = rg;
            *(float4*)&Us[nb][kG][cG] = ru;
        }
        __syncthreads();
    }

#pragma unroll
    for (int i = 0; i < 4; ++i) {
        int r = ty * 4 + i;
        int pr = s_pair[r];
        if (pr < 0) continue;
        float w = pair_w[pr];
        float* ap = act + (size_t)pr * INTER + i0 + tx * 4;
        float4 o;
        float g, u;
        g = accg[i][0]; u = accu[i][0]; o.x = (g / (1.f + expf(-g))) * u * w;
        g = accg[i][1]; u = accu[i][1]; o.y = (g / (1.f + expf(-g))) * u * w;
        g = accg[i][2]; u = accu[i][2]; o.z = (g / (1.f + expf(-g))) * u * w;
        g = accg[i][3]; u = accu[i][3]; o.w = (g / (1.f + expf(-g))) * u * w;
        *(float4*)ap = o;
    }
}

// ---------------- MoE down: 64-token x 64-col tile, double-buffered, z-split ----------------
__global__ __launch_bounds__(256) void moe_down_kernel(
    const float* __restrict__ act, const float* __restrict__ Wd,
    const int* __restrict__ cnt, const int* __restrict__ lst_tok,
    const int* __restrict__ lst_pair, float* __restrict__ acc_out) {
    int e = blockIdx.x;
    int n = cnt[e];
    int t0 = blockIdx.z * 64;
    if (t0 >= n) return;
    int c0 = blockIdx.y * 64;
    int tid = threadIdx.x;
    int tx = tid & 15, ty = tid >> 4;
    __shared__ __align__(16) float As[2][16][68];
    __shared__ __align__(16) float Ws[2][16][68];
    __shared__ int s_tok[64], s_pair[64];
    if (tid < 64) {
        bool ok = (t0 + tid) < n;
        s_tok[tid]  = ok ? lst_tok[e * T_TOK + t0 + tid] : -1;
        s_pair[tid] = ok ? lst_pair[e * T_TOK + t0 + tid] : -1;
    }
    __syncthreads();

    int rA = tid >> 2, kA = (tid & 3) * 4;
    int pr = s_pair[rA]; if (pr < 0) pr = 0;
    int kB = tid >> 4, cB = (tid & 15) * 4;
    const float* ap = act + (size_t)pr * INTER + kA;
    const float* wp = Wd + (size_t)e * INTER * HID + (size_t)kB * HID + c0 + cB;

    float4 ra = *(const float4*)(ap);
    float4 rb = *(const float4*)(wp);
    As[0][kA + 0][rA] = ra.x; As[0][kA + 1][rA] = ra.y;
    As[0][kA + 2][rA] = ra.z; As[0][kA + 3][rA] = ra.w;
    *(float4*)&Ws[0][kB][cB] = rb;
    __syncthreads();

    float acc[4][4] = {};
    const int NKt = INTER / 16;
    for (int kt = 0; kt < NKt; ++kt) {
        int cur = kt & 1;
        bool more = (kt + 1 < NKt);
        if (more) {
            int k0 = (kt + 1) * 16;
            ra = *(const float4*)(ap + k0);
            rb = *(const float4*)(wp + (size_t)k0 * HID);
        }
#pragma unroll
        for (int kk = 0; kk < 16; ++kk) {
            float4 av = *(const float4*)&As[cur][kk][ty * 4];
            float4 bv = *(const float4*)&Ws[cur][kk][tx * 4];
            float a[4] = {av.x, av.y, av.z, av.w};
            float b[4] = {bv.x, bv.y, bv.z, bv.w};
#pragma unroll
            for (int i = 0; i < 4; ++i)
#pragma unroll
                for (int j = 0; j < 4; ++j) acc[i][j] += a[i] * b[j];
        }
        if (more) {
            int nb = cur ^ 1;
            As[nb][kA + 0][rA] = ra.x; As[nb][kA + 1][rA] = ra.y;
            As[nb][kA + 2][rA] = ra.z; As[nb][kA + 3][rA] = ra.w;
            *(float4*)&Ws[nb][kB][cB] = rb;
        }
        __syncthreads();
    }

#pragma unroll
    for (int i = 0; i < 4; ++i) {
        int r = ty * 4 + i;
        int tok = s_tok[r];
        if (tok < 0) continue;
        float* op = acc_out + (size_t)tok * HID + c0 + tx * 4;
#pragma unroll
        for (int j = 0; j < 4; ++j)
            atomicAdd(op + j, acc[i][j]);
    }
}

// ---------------- final: out = x + moe ----------------
__global__ void final_add_kernel(const float* __restrict__ x, const float* __restrict__ moe,
                                 float* __restrict__ out) {
    int i = blockIdx.x * 256 + threadIdx.x;
    out[i] = x[i] + moe[i];
}

extern "C" void kernel_launch(void* const* d_in, const int* in_sizes, int n_in,
                              void* d_out, int out_size, void* d_ws, size_t ws_size,
                              hipStream_t stream) {
    const int*   positions = (const int*)d_in[0];
    const float* hidden    = (const float*)d_in[1];
    const float* Wqkv      = (const float*)d_in[2];
    const float* Wo        = (const float*)d_in[3];
    const float* q_norm_w  = (const float*)d_in[4];
    const float* k_norm_w  = (const float*)d_in[5];
    const float* in_ln_w   = (const float*)d_in[6];
    const float* post_ln_w = (const float*)d_in[7];
    const float* Wg        = (const float*)d_in[8];
    const float* Wgu       = (const float*)d_in[9];
    const float* Wd        = (const float*)d_in[10];
    float* out = (float*)d_out;

    char* ws = (char*)d_ws;
    size_t off = 0;
    auto alloc = [&](size_t bytes) { char* p = ws + off; off += (bytes + 255) & ~(size_t)255; return p; };
    float* bufA     = (float*)alloc((size_t)T_TOK * HID * 4);
    float* bufB     = (float*)alloc((size_t)T_TOK * 8 * INTER * 4);
    float* x        = (float*)alloc((size_t)T_TOK * HID * 4);
    float* acc_moe  = (float*)alloc((size_t)T_TOK * HID * 4);
    int*   cnt      = (int*)alloc(NE * 4);
    int*   lst_tok  = (int*)alloc((size_t)NE * T_TOK * 4);
    int*   lst_pair = (int*)alloc((size_t)NE * T_TOK * 4);
    float* pair_w   = (float*)alloc((size_t)T_TOK * 8 * 4);

    float* h        = bufA;
    float* attn_out = bufA;
    float* h2       = bufA;
    float* qkv      = bufB;
    float* act      = bufB;

    hipMemsetAsync(cnt, 0, NE * 4, stream);
    hipMemsetAsync(acc_moe, 0, (size_t)T_TOK * HID * 4, stream);

    rms_kernel<<<T_TOK, 256, 0, stream>>>(hidden, in_ln_w, h);
    gemm_f32<<<dim3(QKV_N / 64, T_TOK / 64), 256, 0, stream>>>(h, Wqkv, qkv, nullptr, T_TOK, QKV_N, HID);
    qk_rope_kernel<<<T_TOK * (NH + NKV), 64, 0, stream>>>(qkv, positions, q_norm_w, k_norm_w);
    flash_attn_kernel<<<dim3(NH, T_TOK / 64), 256, 0, stream>>>(qkv, attn_out);
    gemm_f32<<<dim3(HID / 64, T_TOK / 64), 256, 0, stream>>>(attn_out, Wo, x, hidden, T_TOK, HID, HID);
    rms_kernel<<<T_TOK, 256, 0, stream>>>(x, post_ln_w, h2);
    route_kernel<<<T_TOK, 64, 0, stream>>>(h2, Wg, cnt, lst_tok, lst_pair, pair_w);
    moe_gateup_kernel<<<dim3(NE, INTER / 64, T_TOK / 64), 256, 0, stream>>>(h2, Wgu, cnt, lst_tok, lst_pair, pair_w, act);
    moe_down_kernel<<<dim3(NE, HID / 64, T_TOK / 64), 256, 0, stream>>>(act, Wd, cnt, lst_tok, lst_pair, acc_moe);
    final_add_kernel<<<(T_TOK * HID) / 256, 256, 0, stream>>>(x, acc_moe, out);
}

// Round 5
// 899.164 us; speedup vs baseline: 5.2517x; 1.3321x over previous
//
#include <hip/hip_runtime.h>

#define T_TOK 1024
#define HID 1024
#define NH 16
#define NKV 4
#define HDIM 64
#define NE 64
#define INTER 512
#define QKV_N 1536

typedef __attribute__((ext_vector_type(8))) short short8;
typedef __attribute__((ext_vector_type(4))) float f32x4;
typedef unsigned short ushort_t;
typedef unsigned int uint_t;

__device__ __forceinline__ ushort_t f2bf(float x) {
    uint_t u = __float_as_uint(x);
    u += 0x7FFFu + ((u >> 16) & 1u);   // RNE
    return (ushort_t)(u >> 16);
}
__device__ __forceinline__ uint_t pack2bf(float a, float b) {
    return (uint_t)f2bf(a) | ((uint_t)f2bf(b) << 16);
}

// ---------------- RMSNorm (f32 input) ----------------
__global__ void rms_kernel(const float* __restrict__ x, const float* __restrict__ w,
                           float* __restrict__ out) {
    int t = blockIdx.x, tid = threadIdx.x;
    __shared__ float red[256];
    const float* xp = x + (size_t)t * HID;
    float v[4]; float ss = 0.f;
    for (int j = 0; j < 4; ++j) { v[j] = xp[tid * 4 + j]; ss += v[j] * v[j]; }
    red[tid] = ss; __syncthreads();
    for (int s = 128; s > 0; s >>= 1) { if (tid < s) red[tid] += red[tid + s]; __syncthreads(); }
    float r = rsqrtf(red[0] / (float)HID + 1e-6f);
    for (int j = 0; j < 4; ++j)
        out[(size_t)t * HID + tid * 4 + j] = v[j] * r * w[tid * 4 + j];
}

// ---------------- Dense GEMM: C(MxN) = A(MxK) @ B(KxN) [+ addend] ----------------
__global__ __launch_bounds__(256) void gemm_f32(
    const float* __restrict__ A, const float* __restrict__ B,
    float* __restrict__ C, const float* __restrict__ addend,
    int M, int N, int K) {
    int row0 = blockIdx.y * 64, col0 = blockIdx.x * 64;
    int tid = threadIdx.x;
    int tx = tid & 15, ty = tid >> 4;
    __shared__ __align__(16) float As[2][16][68];   // [k][m]
    __shared__ __align__(16) float Bs[2][16][68];   // [k][n]

    int rA = tid >> 2, kA = (tid & 3) * 4;
    int kB = tid >> 4, cB = (tid & 15) * 4;
    const float* pa = A + (size_t)(row0 + rA) * K + kA;
    const float* pb = B + (size_t)kB * N + col0 + cB;

    float4 ra = *(const float4*)(pa);
    float4 rb = *(const float4*)(pb);
    As[0][kA + 0][rA] = ra.x; As[0][kA + 1][rA] = ra.y;
    As[0][kA + 2][rA] = ra.z; As[0][kA + 3][rA] = ra.w;
    *(float4*)&Bs[0][kB][cB] = rb;
    __syncthreads();

    float acc[4][4] = {};
    int NKt = K / 16;
    for (int kt = 0; kt < NKt; ++kt) {
        int cur = kt & 1;
        bool more = (kt + 1 < NKt);
        if (more) {
            int k0 = (kt + 1) * 16;
            ra = *(const float4*)(pa + k0);
            rb = *(const float4*)(pb + (size_t)k0 * N);
        }
#pragma unroll
        for (int kk = 0; kk < 16; ++kk) {
            float4 av = *(const float4*)&As[cur][kk][ty * 4];
            float4 bv = *(const float4*)&Bs[cur][kk][tx * 4];
            float a[4] = {av.x, av.y, av.z, av.w};
            float b[4] = {bv.x, bv.y, bv.z, bv.w};
#pragma unroll
            for (int i = 0; i < 4; ++i)
#pragma unroll
                for (int j = 0; j < 4; ++j) acc[i][j] += a[i] * b[j];
        }
        if (more) {
            int nb = cur ^ 1;
            As[nb][kA + 0][rA] = ra.x; As[nb][kA + 1][rA] = ra.y;
            As[nb][kA + 2][rA] = ra.z; As[nb][kA + 3][rA] = ra.w;
            *(float4*)&Bs[nb][kB][cB] = rb;
        }
        __syncthreads();
    }
#pragma unroll
    for (int i = 0; i < 4; ++i) {
        size_t r = row0 + ty * 4 + i;
        size_t c = col0 + tx * 4;
        float4 v = make_float4(acc[i][0], acc[i][1], acc[i][2], acc[i][3]);
        if (addend) {
            const float4 ad = *(const float4*)&addend[r * N + c];
            v.x += ad.x; v.y += ad.y; v.z += ad.z; v.w += ad.w;
        }
        *(float4*)&C[r * N + c] = v;
    }
}

// ---------------- per-head RMSNorm + RoPE on q,k (in-place in qkv f32) ----------------
__global__ void qk_rope_kernel(float* __restrict__ qkv, const int* __restrict__ pos,
                               const float* __restrict__ qw, const float* __restrict__ kw) {
    int b = blockIdx.x;
    int t = b / (NH + NKV), hh = b % (NH + NKV);
    int lane = threadIdx.x;
    bool isq = hh < NH;
    int off = isq ? hh * HDIM : NH * HDIM + (hh - NH) * HDIM;
    const float* w = isq ? qw : kw;
    float* p = qkv + (size_t)t * QKV_N + off;
    float x = p[lane];
    float ss = x * x;
    for (int m = 1; m < 64; m <<= 1) ss += __shfl_xor(ss, m, 64);
    float r = rsqrtf(ss / (float)HDIM + 1e-6f);
    x = x * r * w[lane];
    float partner = __shfl_xor(x, 32, 64);
    int i = lane & 31;
    float freq = expf(-(float)i * (9.21034037198f / 32.f));  // 10000^(-i/32)
    float f = (float)pos[t] * freq;
    float c = cosf(f), s = sinf(f);
    float outv = (lane < 32) ? (x * c - partner * s) : (x * c + partner * s);
    p[lane] = outv;
}

// ---------------- flash attention: one block per (head, 64-query tile) ----------------
__global__ __launch_bounds__(256) void flash_attn_kernel(
    const float* __restrict__ qkv, float* __restrict__ attn_out) {
    int h = blockIdx.x;
    int qt = 15 - blockIdx.y;
    int kh = h >> 2;
    int tid = threadIdx.x;
    int tx = tid & 15, ty = tid >> 4;

    __shared__ __align__(16) float Qs[64][68];    // [d][q]
    __shared__ __align__(16) float KPs[64][68];   // K^T: [d][kv] then P: [kv][q]
    __shared__ __align__(16) float Vs[64][68];    // [kv][d]

    int r = tid >> 2;
    int c0 = (tid & 3) * 4;

    {
        const float* qp = qkv + (size_t)(qt * 64 + r) * QKV_N + h * HDIM;
#pragma unroll
        for (int cc = 0; cc < 4; ++cc) {
            int d = c0 + cc * 16;
            float4 fq = *(const float4*)(qp + d);
            Qs[d + 0][r] = fq.x; Qs[d + 1][r] = fq.y;
            Qs[d + 2][r] = fq.z; Qs[d + 3][r] = fq.w;
        }
    }

    const float* kp = qkv + (size_t)r * QKV_N + NH * HDIM + kh * HDIM;
    const float* vp = qkv + (size_t)r * QKV_N + (NH + NKV) * HDIM + kh * HDIM;

    float m[4], l[4], accO[4][4] = {};
#pragma unroll
    for (int i = 0; i < 4; ++i) { m[i] = -1e30f; l[i] = 0.f; }

    for (int kt = 0; kt <= qt; ++kt) {
        size_t toff = (size_t)kt * 64 * QKV_N;
        float4 fk[4], fv[4];
#pragma unroll
        for (int cc = 0; cc < 4; ++cc) {
            fk[cc] = *(const float4*)(kp + toff + c0 + cc * 16);
            fv[cc] = *(const float4*)(vp + toff + c0 + cc * 16);
        }
        __syncthreads();
#pragma unroll
        for (int cc = 0; cc < 4; ++cc) {
            int d = c0 + cc * 16;
            KPs[d + 0][r] = fk[cc].x; KPs[d + 1][r] = fk[cc].y;
            KPs[d + 2][r] = fk[cc].z; KPs[d + 3][r] = fk[cc].w;
            *(float4*)&Vs[r][d] = fv[cc];
        }
        __syncthreads();

        float s[4][4] = {};
#pragma unroll 16
        for (int kk = 0; kk < 64; ++kk) {
            float4 qa = *(const float4*)&Qs[kk][ty * 4];
            float4 kb = *(const float4*)&KPs[kk][tx * 4];
            float a[4] = {qa.x, qa.y, qa.z, qa.w};
            float b[4] = {kb.x, kb.y, kb.z, kb.w};
#pragma unroll
            for (int i = 0; i < 4; ++i)
#pragma unroll
                for (int j = 0; j < 4; ++j) s[i][j] += a[i] * b[j];
        }
#pragma unroll
        for (int i = 0; i < 4; ++i)
#pragma unroll
            for (int j = 0; j < 4; ++j) s[i][j] *= 0.125f;

        if (kt == qt) {
#pragma unroll
            for (int i = 0; i < 4; ++i)
#pragma unroll
                for (int j = 0; j < 4; ++j)
                    if (tx * 4 + j > ty * 4 + i) s[i][j] = -1e30f;
        }

#pragma unroll
        for (int i = 0; i < 4; ++i) {
            float rm = fmaxf(fmaxf(s[i][0], s[i][1]), fmaxf(s[i][2], s[i][3]));
            rm = fmaxf(rm, __shfl_xor(rm, 1, 64));
            rm = fmaxf(rm, __shfl_xor(rm, 2, 64));
            rm = fmaxf(rm, __shfl_xor(rm, 4, 64));
            rm = fmaxf(rm, __shfl_xor(rm, 8, 64));
            float mn = fmaxf(m[i], rm);
            float sc = __expf(m[i] - mn);
            float ps = 0.f;
#pragma unroll
            for (int j = 0; j < 4; ++j) {
                float p = __expf(s[i][j] - mn);
                s[i][j] = p; ps += p;
            }
            ps += __shfl_xor(ps, 1, 64);
            ps += __shfl_xor(ps, 2, 64);
            ps += __shfl_xor(ps, 4, 64);
            ps += __shfl_xor(ps, 8, 64);
            l[i] = l[i] * sc + ps;
            m[i] = mn;
#pragma unroll
            for (int j = 0; j < 4; ++j) accO[i][j] *= sc;
        }

        __syncthreads();
#pragma unroll
        for (int i = 0; i < 4; ++i)
#pragma unroll
            for (int j = 0; j < 4; ++j)
                KPs[tx * 4 + j][ty * 4 + i] = s[i][j];
        __syncthreads();

#pragma unroll 16
        for (int kk = 0; kk < 64; ++kk) {
            float4 pa = *(const float4*)&KPs[kk][ty * 4];
            float4 vb = *(const float4*)&Vs[kk][tx * 4];
            float a[4] = {pa.x, pa.y, pa.z, pa.w};
            float b[4] = {vb.x, vb.y, vb.z, vb.w};
#pragma unroll
            for (int i = 0; i < 4; ++i)
#pragma unroll
                for (int j = 0; j < 4; ++j) accO[i][j] += a[i] * b[j];
        }
    }

#pragma unroll
    for (int i = 0; i < 4; ++i) {
        float inv = 1.f / l[i];
        int row = qt * 64 + ty * 4 + i;
        float4 o = make_float4(accO[i][0] * inv, accO[i][1] * inv,
                               accO[i][2] * inv, accO[i][3] * inv);
        *(float4*)&attn_out[(size_t)row * HID + h * HDIM + tx * 4] = o;
    }
}

// ---------------- router ----------------
__global__ void route_kernel(const float* __restrict__ h2, const float* __restrict__ Wg,
                             int* __restrict__ cnt, int* __restrict__ lst_tok,
                             int* __restrict__ lst_pair, float* __restrict__ pair_w) {
    int t = blockIdx.x, j = threadIdx.x;
    const float* hp = h2 + (size_t)t * HID;
    float acc = 0.f;
    for (int k = 0; k < HID; ++k) acc += hp[k] * Wg[(size_t)k * NE + j];
    float mx = acc;
    for (int m = 1; m < 64; m <<= 1) mx = fmaxf(mx, __shfl_xor(mx, m, 64));
    float e = expf(acc - mx);
    float sm = e;
    for (int m = 1; m < 64; m <<= 1) sm += __shfl_xor(sm, m, 64);
    float p = e / sm;
    float bp = p; int bi = j;
    for (int m = 1; m < 8; m <<= 1) {
        float op = __shfl_xor(bp, m, 64);
        int oi = __shfl_xor(bi, m, 64);
        if (op > bp || (op == bp && oi < bi)) { bp = op; bi = oi; }
    }
    __shared__ float gw[8]; __shared__ int gi[8];
    if ((j & 7) == 0) { gw[j >> 3] = bp; gi[j >> 3] = bi; }
    __syncthreads();
    if (j < 8) {
        float tw = gw[j];
        float wsum = tw;
        for (int m = 1; m < 8; m <<= 1) wsum += __shfl_xor(wsum, m, 64);
        float w = tw / wsum;
        int ei = gi[j];
        int pos = atomicAdd(&cnt[ei], 1);
        lst_tok[ei * T_TOK + pos] = t;
        lst_pair[ei * T_TOK + pos] = t * 8 + j;
        pair_w[t * 8 + j] = w;
    }
}

// ---------------- MoE gate_up via bf16 MFMA ----------------
// 64-token x (64g + 64u) tile, K-chunks of 32, frag-linear LDS for W (cvt f32->bf16
// at staging), A-frags direct from h2 (f32->bf16 in-reg). 4 waves x 16 rows.
// LDS frag layout per coltile ct (stride 520 ushorts): lane L holds 16B at L*8,
// elem b = k&7, L = (col&15) + 16*(k>>3)  [contiguous-k frag, m92-verified].
__global__ __launch_bounds__(256) void moe_gateup_kernel(
    const float* __restrict__ h2, const float* __restrict__ Wgu,
    const int* __restrict__ cnt, const int* __restrict__ lst_tok,
    const int* __restrict__ lst_pair, const float* __restrict__ pair_w,
    ushort_t* __restrict__ act) {
    int e = blockIdx.x;
    int n = cnt[e];
    int t0 = blockIdx.z * 64;
    if (t0 >= n) return;
    int i0 = blockIdx.y * 64;
    int tid = threadIdx.x;

    __shared__ ushort_t Bsh[2][8 * 520];
    __shared__ int s_tok[64], s_pair[64];
    if (tid < 64) {
        bool ok = (t0 + tid) < n;
        s_tok[tid]  = ok ? lst_tok[e * T_TOK + t0 + tid] : -1;
        s_pair[tid] = ok ? lst_pair[e * T_TOK + t0 + tid] : -1;
    }
    __syncthreads();

    // --- staging coords: thread -> k-pair p (rows 2p,2p+1), 8 cols at cbase ---
    int p = tid >> 4;                 // 0..15
    int cbase = (tid & 15) * 8;       // 0..120
    int ct_s = cbase >> 4;
    const float* wbase = Wgu + (size_t)e * HID * (2 * INTER)
        + (cbase < 64 ? (i0 + cbase) : (INTER + i0 + (cbase - 64)));
    int sidx = 260 * ct_s + 4 * ((cbase & 15) + 16 * (p >> 2)) + (p & 3); // u32 units
    uint_t* bs32_0 = (uint_t*)&Bsh[0][0];
    uint_t* bs32_1 = (uint_t*)&Bsh[1][0];

    float wr0[8], wr1[8];
    auto ldW = [&](int k0) {
        const float* r0 = wbase + (size_t)(k0 + 2 * p) * (2 * INTER);
        *(float4*)&wr0[0] = *(const float4*)(r0);
        *(float4*)&wr0[4] = *(const float4*)(r0 + 4);
        *(float4*)&wr1[0] = *(const float4*)(r0 + 2 * INTER);
        *(float4*)&wr1[4] = *(const float4*)(r0 + 2 * INTER + 4);
    };
    auto stW = [&](uint_t* bs) {
#pragma unroll
        for (int cc = 0; cc < 8; ++cc)
            bs[sidx + 4 * cc] = pack2bf(wr0[cc], wr1[cc]);
    };

    // --- wave coords ---
    int wv = tid >> 6, ln = tid & 63;
    int rowA = wv * 16 + (ln & 15);
    int tokA = s_tok[rowA]; if (tokA < 0) tokA = 0;
    const float* hpA = h2 + (size_t)tokA * HID + 8 * (ln >> 4);

    float a0[8], a1[8];
    auto ldA = [&](int k0, float* a) {
        const float* pa = hpA + k0;
        *(float4*)&a[0] = *(const float4*)(pa);
        *(float4*)&a[4] = *(const float4*)(pa + 4);
    };
    auto packA = [&](const float* a) {
        short8 s;
        uint_t* up = (uint_t*)&s;
        up[0] = pack2bf(a[0], a[1]); up[1] = pack2bf(a[2], a[3]);
        up[2] = pack2bf(a[4], a[5]); up[3] = pack2bf(a[6], a[7]);
        return s;
    };

    f32x4 acc[8] = {};
    const int NC = HID / 32;  // 32 chunks

    ldW(0); ldA(0, a0);
    stW(bs32_0);
    __syncthreads();

    auto body = [&](int kt, float* aCur, float* aNxt, uint_t* cur, uint_t* nxt) {
        bool more = (kt + 1 < NC);
        if (more) { ldW((kt + 1) * 32); ldA((kt + 1) * 32, aNxt); }
        short8 aF = packA(aCur);
        const ushort_t* cb = (const ushort_t*)cur;
#pragma unroll
        for (int ct = 0; ct < 8; ++ct) {
            short8 bF = *(const short8*)(cb + ct * 520 + ln * 8);
            acc[ct] = __builtin_amdgcn_mfma_f32_16x16x32_bf16(aF, bF, acc[ct], 0, 0, 0);
        }
        if (more) stW(nxt);
        __syncthreads();
    };
    for (int kt = 0; kt < NC; kt += 2) {
        body(kt,     a0, a1, bs32_0, bs32_1);
        body(kt + 1, a1, a0, bs32_1, bs32_0);
    }

    // --- epilogue: D row = (ln>>4)*4 + r, col = ln&15 (m89-verified) ---
#pragma unroll
    for (int r = 0; r < 4; ++r) {
        int rowl = wv * 16 + 4 * (ln >> 4) + r;
        int pr = s_pair[rowl];
        if (pr < 0) continue;
        float w = pair_w[pr];
        ushort_t* ap = act + (size_t)pr * INTER + i0 + (ln & 15);
#pragma unroll
        for (int ct = 0; ct < 4; ++ct) {
            float g = acc[ct][r];
            float u = acc[ct + 4][r];
            float silu = g / (1.f + __expf(-g));
            ap[ct * 16] = f2bf(silu * u * w);
        }
    }
}

// ---------------- MoE down via bf16 MFMA: 64 tok x 64 cols ----------------
__global__ __launch_bounds__(256) void moe_down_kernel(
    const ushort_t* __restrict__ act, const float* __restrict__ Wd,
    const int* __restrict__ cnt, const int* __restrict__ lst_tok,
    const int* __restrict__ lst_pair, float* __restrict__ acc_out) {
    int e = blockIdx.x;
    int n = cnt[e];
    int t0 = blockIdx.z * 64;
    if (t0 >= n) return;
    int c0 = blockIdx.y * 64;
    int tid = threadIdx.x;

    __shared__ ushort_t Bsh[2][4 * 520];
    __shared__ int s_tok[64], s_pair[64];
    if (tid < 64) {
        bool ok = (t0 + tid) < n;
        s_tok[tid]  = ok ? lst_tok[e * T_TOK + t0 + tid] : -1;
        s_pair[tid] = ok ? lst_pair[e * T_TOK + t0 + tid] : -1;
    }
    __syncthreads();

    int p = tid >> 4;              // k-pair 0..15
    int cbase = (tid & 15) * 4;    // 0..60
    int ct_s = cbase >> 4;
    const float* wbase = Wd + (size_t)e * INTER * HID + c0 + cbase;
    int sidx = 260 * ct_s + 4 * ((cbase & 15) + 16 * (p >> 2)) + (p & 3);
    uint_t* bs32_0 = (uint_t*)&Bsh[0][0];
    uint_t* bs32_1 = (uint_t*)&Bsh[1][0];

    float wr0[4], wr1[4];
    auto ldW = [&](int k0) {
        const float* r0 = wbase + (size_t)(k0 + 2 * p) * HID;
        *(float4*)&wr0[0] = *(const float4*)(r0);
        *(float4*)&wr1[0] = *(const float4*)(r0 + HID);
    };
    auto stW = [&](uint_t* bs) {
#pragma unroll
        for (int cc = 0; cc < 4; ++cc)
            bs[sidx + 4 * cc] = pack2bf(wr0[cc], wr1[cc]);
    };

    int wv = tid >> 6, ln = tid & 63;
    int rowA = wv * 16 + (ln & 15);
    int prA = s_pair[rowA]; if (prA < 0) prA = 0;
    const ushort_t* apA = act + (size_t)prA * INTER + 8 * (ln >> 4);

    f32x4 acc[4] = {};
    const int NC = INTER / 32;  // 16 chunks
    short8 a0, a1;

    ldW(0);
    a0 = *(const short8*)(apA);
    stW(bs32_0);
    __syncthreads();

    auto body = [&](int kt, short8 aCur, short8* aNxt, uint_t* cur, uint_t* nxt) {
        bool more = (kt + 1 < NC);
        if (more) { ldW((kt + 1) * 32); *aNxt = *(const short8*)(apA + (kt + 1) * 32); }
        const ushort_t* cb = (const ushort_t*)cur;
#pragma unroll
        for (int ct = 0; ct < 4; ++ct) {
            short8 bF = *(const short8*)(cb + ct * 520 + ln * 8);
            acc[ct] = __builtin_amdgcn_mfma_f32_16x16x32_bf16(aCur, bF, acc[ct], 0, 0, 0);
        }
        if (more) stW(nxt);
        __syncthreads();
    };
    for (int kt = 0; kt < NC; kt += 2) {
        body(kt,     a0, &a1, bs32_0, bs32_1);
        body(kt + 1, a1, &a0, bs32_1, bs32_0);
    }

#pragma unroll
    for (int r = 0; r < 4; ++r) {
        int rowl = wv * 16 + 4 * (ln >> 4) + r;
        int tok = s_tok[rowl];
        if (tok < 0) continue;
        float* op = acc_out + (size_t)tok * HID + c0 + (ln & 15);
#pragma unroll
        for (int ct = 0; ct < 4; ++ct)
            atomicAdd(op + ct * 16, acc[ct][r]);
    }
}

// ---------------- final: out = x + moe ----------------
__global__ void final_add_kernel(const float* __restrict__ x, const float* __restrict__ moe,
                                 float* __restrict__ out) {
    int i = blockIdx.x * 256 + threadIdx.x;
    out[i] = x[i] + moe[i];
}

extern "C" void kernel_launch(void* const* d_in, const int* in_sizes, int n_in,
                              void* d_out, int out_size, void* d_ws, size_t ws_size,
                              hipStream_t stream) {
    const int*   positions = (const int*)d_in[0];
    const float* hidden    = (const float*)d_in[1];
    const float* Wqkv      = (const float*)d_in[2];
    const float* Wo        = (const float*)d_in[3];
    const float* q_norm_w  = (const float*)d_in[4];
    const float* k_norm_w  = (const float*)d_in[5];
    const float* in_ln_w   = (const float*)d_in[6];
    const float* post_ln_w = (const float*)d_in[7];
    const float* Wg        = (const float*)d_in[8];
    const float* Wgu       = (const float*)d_in[9];
    const float* Wd        = (const float*)d_in[10];
    float* out = (float*)d_out;

    char* ws = (char*)d_ws;
    size_t off = 0;
    auto alloc = [&](size_t bytes) { char* p = ws + off; off += (bytes + 255) & ~(size_t)255; return p; };
    float* bufA     = (float*)alloc((size_t)T_TOK * HID * 4);
    float* bufB     = (float*)alloc((size_t)T_TOK * 8 * INTER * 4);   // qkv f32 then act bf16
    float* x        = (float*)alloc((size_t)T_TOK * HID * 4);
    float* acc_moe  = (float*)alloc((size_t)T_TOK * HID * 4);
    int*   cnt      = (int*)alloc(NE * 4);
    int*   lst_tok  = (int*)alloc((size_t)NE * T_TOK * 4);
    int*   lst_pair = (int*)alloc((size_t)NE * T_TOK * 4);
    float* pair_w   = (float*)alloc((size_t)T_TOK * 8 * 4);

    float*    h        = bufA;
    float*    attn_out = bufA;
    float*    h2       = bufA;
    float*    qkv      = bufB;
    ushort_t* act      = (ushort_t*)bufB;

    hipMemsetAsync(cnt, 0, NE * 4, stream);
    hipMemsetAsync(acc_moe, 0, (size_t)T_TOK * HID * 4, stream);

    rms_kernel<<<T_TOK, 256, 0, stream>>>(hidden, in_ln_w, h);
    gemm_f32<<<dim3(QKV_N / 64, T_TOK / 64), 256, 0, stream>>>(h, Wqkv, qkv, nullptr, T_TOK, QKV_N, HID);
    qk_rope_kernel<<<T_TOK * (NH + NKV), 64, 0, stream>>>(qkv, positions, q_norm_w, k_norm_w);
    flash_attn_kernel<<<dim3(NH, T_TOK / 64), 256, 0, stream>>>(qkv, attn_out);
    gemm_f32<<<dim3(HID / 64, T_TOK / 64), 256, 0, stream>>>(attn_out, Wo, x, hidden, T_TOK, HID, HID);
    rms_kernel<<<T_TOK, 256, 0, stream>>>(x, post_ln_w, h2);
    route_kernel<<<T_TOK, 64, 0, stream>>>(h2, Wg, cnt, lst_tok, lst_pair, pair_w);
    moe_gateup_kernel<<<dim3(NE, INTER / 64, T_TOK / 64), 256, 0, stream>>>(h2, Wgu, cnt, lst_tok, lst_pair, pair_w, act);
    moe_down_kernel<<<dim3(NE, HID / 64, T_TOK / 64), 256, 0, stream>>>(act, Wd, cnt, lst_tok, lst_pair, acc_moe);
    final_add_kernel<<<(T_TOK * HID) / 256, 256, 0, stream>>>(x, acc_moe, out);
}